// Round 9
// baseline (2781.508 us; speedup 1.0000x reference)
//
#include <hip/hip_runtime.h>
#include <cstddef>
#include <cstdint>

// Model dims (fixed by reference)
#define T_LEN 512
#define B_SZ  128
#define MD    31
#define E_SZ  256
#define H_SZ  512
#define S_SZ  128
#define GAMMA_F 1.0f
#define LOG001   -4.605170185988091f   // log(0.01)
#define HALF_L2PI 0.9189385332046727f  // 0.5*log(2*pi)

typedef __attribute__((ext_vector_type(8))) short bf16x8;   // 8 bf16 in 4 VGPRs
typedef __attribute__((ext_vector_type(4))) float f32x4;

#define ACT_PITCH 536   // shorts: 512 + 24 pad
#define PHI_PITCH 264   // shorts: 256 + 8 pad
#define GP        36    // gate-array col pitch (floats)
#define HS_PITCH  516   // loss hs tile pitch (floats)
#define WM_PITCH  132   // loss wmu/wlv pitch (ushorts)
#define CNT_STRIDE 16   // dwords: one 64B line per counter
#define CNT_MAGIC  0x7E5A0000u   // high-16 marker: distinguishes real counters from 0xAA poison

// ---- shared-memory union (max of recurrence 45.3KB / loss 58.2KB) ----
#define SMEM_BYTES 58240
// recurrence offsets
#define R_ACT  0
#define R_PHI  17152
#define R_GS   34048
#define R_XS   43264   // fp32 x tile [16][32]
// loss offsets
#define L_HST  0
#define L_HES  33024
#define L_WMU  41280
#define L_WLV  49464
#define L_HINF 57648

__device__ inline unsigned short f2bf(float f) {   // fp32 -> bf16 bits, RNE
    union { float f; unsigned u; } v; v.f = f;
    unsigned r = v.u + 0x7FFFu + ((v.u >> 16) & 1u);
    return (unsigned short)(r >> 16);
}
__device__ inline float bf2f(unsigned short u) {
    union { unsigned u; float f; } v; v.u = (unsigned)u << 16; return v.f;
}
__device__ inline unsigned long long llc_load_u64(const unsigned long long* p) {
    return __hip_atomic_load(p, __ATOMIC_RELAXED, __HIP_MEMORY_SCOPE_AGENT);
}
__device__ inline unsigned llc_load_u32(const unsigned* p) {
    return __hip_atomic_load(p, __ATOMIC_RELAXED, __HIP_MEMORY_SCOPE_AGENT);
}

// ---------------- single fused persistent kernel: 128 recurrence + 128 loss blocks ----------
// All former pre-kernels folded in:
//  - weights: B-fragments converted fp32->bf16 in-register at init (pack_w gone)
//  - phi: computed in-kernel per step on the gate threads, LDS-only (embed_phi gone)
//  - init: blocks zero their own hx slot (tag-poll self-syncs); cnt is magic-tagged so
//    0xAA poison reads as not-ready; loss block 0 zeroes out[0] (adds gated ~1ms later)
__global__ __launch_bounds__(384) void fused_persist(
    const float* __restrict__ W_ih, const float* __restrict__ W_hh,
    unsigned* __restrict__ hx, float* __restrict__ hs,
    const float* __restrict__ b_ih, const float* __restrict__ b_hh,
    unsigned* __restrict__ cnt,
    const float* __restrict__ W_embed, const float* __restrict__ b_embed,
    const float* __restrict__ W_he, const float* __restrict__ b_he,
    const float* __restrict__ W_mu, const float* __restrict__ b_mu,
    const float* __restrict__ W_lv, const float* __restrict__ b_lv,
    const float* __restrict__ h_inf, const float* __restrict__ time_inf,
    const float* __restrict__ base_int, const float* __restrict__ x,
    const float* __restrict__ t_in, const float* __restrict__ mask,
    float* __restrict__ out) {
    __shared__ __align__(16) char smem[SMEM_BYTES];
    const int tid = threadIdx.x;

    if (blockIdx.x < 128) {
        // ================= RECURRENCE PATH =================
        short* act_s  = (short*)(smem + R_ACT);
        short* phi_s0 = (short*)(smem + R_PHI);
        short* phi_s1 = (short*)(smem + R_PHI) + 16 * PHI_PITCH;
        float* g_s    = (float*)(smem + R_GS);     // [4][16*GP]
        float* xs     = (float*)(smem + R_XS);     // [16][32]

        const int bt = blockIdx.x & 7, ct = blockIdx.x >> 3;
        const int b0 = bt * 16, j0 = ct * 32;
        const int wid = tid >> 6, L = tid & 63;
        const int gt = wid >> 1, ch = wid & 1;
        const int n_loc = L & 15, kb2 = L >> 4;
        const int a_row = L & 15;

        // --- zero own hx slot in buf0 (tag0 + h=0 == 0u); consumers retry until it lands ---
        {
            unsigned* own = hx + ((size_t)(0 * 8 + bt) * 16 + ct) * 512;
            __hip_atomic_store(own + tid, 0u, __ATOMIC_RELAXED, __HIP_MEMORY_SCOPE_AGENT);
            if (tid < 128)
                __hip_atomic_store(own + 384 + tid, 0u, __ATOMIC_RELAXED, __HIP_MEMORY_SCOPE_AGENT);
        }

        // --- convert loop-invariant B fragments fp32 -> bf16 in registers (pack_w inlined) ---
        const int col = gt * 512 + j0 + ch * 16 + n_loc;
        bf16x8 Bf[24];
        #pragma unroll
        for (int i = 0; i < 24; ++i) {
            const float* src = (i < 16)
                ? (W_hh + (size_t)col * H_SZ + i * 32 + kb2 * 8)
                : (W_ih + (size_t)col * E_SZ + (i - 16) * 32 + kb2 * 8);
            bf16x8 r;
            #pragma unroll
            for (int k = 0; k < 8; ++k) r[k] = (short)f2bf(src[k]);
            Bf[i] = r;
        }

        // --- per-thread embed weights (threads 0..255: output col e = tid) ---
        float we[MD]; float be = 0.f;
        if (tid < 256) {
            #pragma unroll
            for (int m = 0; m < MD; ++m) we[m] = W_embed[tid * MD + m];
            be = b_embed[tid];
        }

        // --- gate-phase invariants ---
        const int g_row = tid >> 5, g_col = tid & 31;
        float bias_r = 0.f, bias_z = 0.f, bias_xn = 0.f, bias_hn = 0.f;
        if (tid < 256) {
            const int j = j0 + g_col;
            bias_r  = b_ih[j] + b_hh[j];
            bias_z  = b_ih[512 + j] + b_hh[512 + j];
            bias_xn = b_ih[1024 + j];
            bias_hn = b_hh[1024 + j];
        }
        float hold1 = 0.f, hold2 = 0.f;

        // --- phi[0]: x tile -> xs -> embed -> phi_s0 ---
        {
            float xv0 = 0.f, xv1 = 0.f;
            {
                const int c0 = tid;                 // < 496 always (384)
                const int mr = c0 / MD, m = c0 - mr * MD;
                if (c0 < 496) xv0 = x[((size_t)0 * B_SZ + b0 + mr) * MD + m];
                const int c1 = tid + 384;
                if (c1 < 496) {
                    const int mr1 = c1 / MD, m1 = c1 - mr1 * MD;
                    xv1 = x[((size_t)0 * B_SZ + b0 + mr1) * MD + m1];
                }
            }
            if (tid < 496) { const int mr = tid / MD, m = tid - mr * MD; xs[mr * 32 + m] = xv0; }
            if (tid + 384 < 496) {
                const int c1 = tid + 384, mr = c1 / MD, m = c1 - mr * MD; xs[mr * 32 + m] = xv1;
            }
            __syncthreads();
            if (tid < 256) {
                #pragma unroll
                for (int mr = 0; mr < 16; ++mr) {
                    float acc = be;
                    #pragma unroll
                    for (int m = 0; m < MD; ++m) acc = fmaf(xs[mr * 32 + m], we[m], acc);
                    phi_s0[mr * PHI_PITCH + tid] = (short)f2bf(fmaxf(acc, 0.f));
                }
            }
            __syncthreads();
        }

        for (int t = 0; t < T_LEN - 1; ++t) {
            const int buf = t & 1;
            const short* phi_cur = buf ? phi_s1 : phi_s0;
            const unsigned tg = (unsigned)t & 0xFFFFu;
            const int tn = t + 1;

            // (1) issue x[t+1] loads into regs
            float xv0 = 0.f, xv1 = 0.f;
            if (tn < T_LEN - 1) {
                const int mr = tid / MD, m = tid - mr * MD;
                if (tid < 496) xv0 = x[((size_t)tn * B_SZ + b0 + mr) * MD + m];
                const int c1 = tid + 384;
                if (c1 < 496) {
                    const int mr1 = c1 / MD, m1 = c1 - mr1 * MD;
                    xv1 = x[((size_t)tn * B_SZ + b0 + mr1) * MD + m1];
                }
            }

            // (2) phi-part MFMAs now, before the poll (phi_s[cur] ready since last iter)
            f32x4 accP = {0.f, 0.f, 0.f, 0.f};
            {
                const short* prow = phi_cur + a_row * PHI_PITCH;
                #pragma unroll
                for (int i = 16; i < 24; ++i) {
                    bf16x8 a = *(const bf16x8*)(prow + (i - 16) * 32 + kb2 * 8);
                    accP = __builtin_amdgcn_mfma_f32_16x16x32_bf16(a, Bf[i], accP, 0, 0, 0);
                }
            }

            // (3) staging + implicit barrier: poll tagged h words (throttled retries)
            const unsigned long long* hx64 =
                (const unsigned long long*)hx + ((size_t)(buf * 8 + bt)) * 4096;
            unsigned long long v[11];
            #pragma unroll
            for (int it = 0; it < 11; ++it) {
                const int c = tid + it * 384;
                if (c < 4096) v[it] = llc_load_u64(hx64 + c);
            }
            while (true) {
                unsigned bad = 0;
                #pragma unroll
                for (int it = 0; it < 11; ++it) {
                    const int c = tid + it * 384;
                    if (c < 4096) {
                        const unsigned t0 = (unsigned)v[it] & 0xFFFFu;
                        const unsigned t1 = (unsigned)(v[it] >> 32) & 0xFFFFu;
                        if ((t0 ^ tg) | (t1 ^ tg)) bad |= (1u << it);
                    }
                }
                if (bad == 0) break;
                __builtin_amdgcn_s_sleep(1);
                #pragma unroll
                for (int it = 0; it < 11; ++it)
                    if (bad & (1u << it)) v[it] = llc_load_u64(hx64 + tid + it * 384);
            }
            #pragma unroll
            for (int it = 0; it < 11; ++it) {
                const int c = tid + it * 384;
                if (c < 4096) {
                    const int ctp = c >> 8, w = c & 255, row = w >> 4, colp = w & 15;
                    const unsigned lo = (unsigned)(v[it] >> 16) & 0xFFFFu;
                    const unsigned hi = (unsigned)(v[it] >> 48) & 0xFFFFu;
                    *(unsigned*)(act_s + row * ACT_PITCH + ctp * 32 + colp * 2) = lo | (hi << 16);
                }
            }
            // (3b) commit x regs -> xs
            if (tn < T_LEN - 1) {
                if (tid < 496) { const int mr = tid / MD, m = tid - mr * MD; xs[mr * 32 + m] = xv0; }
                if (tid + 384 < 496) {
                    const int c1 = tid + 384, mr = c1 / MD, m = c1 - mr * MD; xs[mr * 32 + m] = xv1;
                }
            }
            __syncthreads();   // sync A
            // publish: hs rows <= t are at LLC (drained by sync A)
            if (tid == 0 && t)
                __hip_atomic_store(cnt + blockIdx.x * CNT_STRIDE, CNT_MAGIC | tg,
                                   __ATOMIC_RELAXED, __HIP_MEMORY_SCOPE_AGENT);

            // (5) h-part MFMAs (split chains) + embed compute for phi[t+1]
            {
                const short* arow = act_s + a_row * ACT_PITCH;
                f32x4 acc0 = {0.f, 0.f, 0.f, 0.f};
                f32x4 acc1 = {0.f, 0.f, 0.f, 0.f};
                #pragma unroll
                for (int i = 0; i < 16; i += 2) {
                    bf16x8 a0 = *(const bf16x8*)(arow + i * 32 + kb2 * 8);
                    bf16x8 a1 = *(const bf16x8*)(arow + (i + 1) * 32 + kb2 * 8);
                    acc0 = __builtin_amdgcn_mfma_f32_16x16x32_bf16(a0, Bf[i], acc0, 0, 0, 0);
                    acc1 = __builtin_amdgcn_mfma_f32_16x16x32_bf16(a1, Bf[i + 1], acc1, 0, 0, 0);
                }
                if (gt < 2) {
                    #pragma unroll
                    for (int i2 = 0; i2 < 4; ++i2)
                        g_s[gt * 16 * GP + ((L >> 4) * 4 + i2) * GP + ch * 16 + n_loc] =
                            acc0[i2] + acc1[i2] + accP[i2];
                } else {
                    #pragma unroll
                    for (int i2 = 0; i2 < 4; ++i2) {
                        const int idx = ((L >> 4) * 4 + i2) * GP + ch * 16 + n_loc;
                        g_s[2 * 16 * GP + idx] = acc0[i2] + acc1[i2];   // hn
                        g_s[3 * 16 * GP + idx] = accP[i2];              // xn
                    }
                }
            }
            if (tn < T_LEN - 1 && tid < 256) {      // embed: phi[t+1] -> other LDS buffer
                short* pdst = (tn & 1) ? phi_s1 : phi_s0;
                #pragma unroll
                for (int mr = 0; mr < 16; ++mr) {
                    float acc = be;
                    #pragma unroll
                    for (int m = 0; m < MD; ++m) acc = fmaf(xs[mr * 32 + m], we[m], acc);
                    pdst[mr * PHI_PITCH + tid] = (short)f2bf(fmaxf(acc, 0.f));
                }
            }
            __syncthreads();   // sync B

            // (7) gate math + state update + tagged store
            if (tid < 256) {
                const int nb = (t + 1) & 1;
                unsigned* hxdst = hx + ((size_t)(nb * 8 + bt) * 16 + ct) * 512;
                #pragma unroll
                for (int half = 0; half < 2; ++half) {
                    const int row = g_row + half * 8;
                    const int idx = row * GP + g_col;
                    float& hold = half ? hold2 : hold1;
                    const float pre_r = g_s[0 * 16 * GP + idx] + bias_r;
                    const float pre_z = g_s[1 * 16 * GP + idx] + bias_z;
                    const float hn    = g_s[2 * 16 * GP + idx] + bias_hn;
                    const float xn    = g_s[3 * 16 * GP + idx] + bias_xn;
                    const float r = 1.f / (1.f + __expf(-pre_r));
                    const float z = 1.f / (1.f + __expf(-pre_z));
                    const float e2 = __expf(-2.f * fmaf(r, hn, xn));
                    const float n = (1.f - e2) / (1.f + e2);          // tanh
                    const float hnew = fmaf(z, hold - n, n);          // (1-z)*n + z*h
                    hold = hnew;
                    __hip_atomic_store(
                        hs + (size_t)(t + 1) * B_SZ * H_SZ + (size_t)(b0 + row) * H_SZ + j0 + g_col,
                        hnew, __ATOMIC_RELAXED, __HIP_MEMORY_SCOPE_AGENT);
                    if (t < T_LEN - 2)
                        __hip_atomic_store(hxdst + row * 32 + g_col,
                                           ((unsigned)f2bf(hnew) << 16) | ((unsigned)(t + 1) & 0xFFFFu),
                                           __ATOMIC_RELAXED, __HIP_MEMORY_SCOPE_AGENT);
                }
            }
        }
        __syncthreads();   // drain final hs stores
        if (tid == 0)
            __hip_atomic_store(cnt + blockIdx.x * CNT_STRIDE, CNT_MAGIC | (unsigned)(T_LEN - 1),
                               __ATOMIC_RELAXED, __HIP_MEMORY_SCOPE_AGENT);
    } else {
        // ================= LOSS PATH =================
        float* hsT  = (float*)(smem + L_HST);            // [16][HS_PITCH]
        float* he_s = (float*)(smem + L_HES);            // [16][129]
        unsigned short* wmu_s = (unsigned short*)(smem + L_WMU);  // [31][WM_PITCH] bf16
        unsigned short* wlv_s = (unsigned short*)(smem + L_WLV);
        float* hinf_s = (float*)(smem + L_HINF);         // [128]
        float* red    = (float*)(smem + L_HINF) + 128;   // [6]

        const int i = blockIdx.x - 128;
        const int lb = i & 7, ls = i >> 3;
        const int b0 = lb * 16;

        if (i == 0 && tid == 0)     // zero the output; adds are cnt-gated ~1ms later
            __hip_atomic_store(out, 0.f, __ATOMIC_RELAXED, __HIP_MEMORY_SCOPE_AGENT);

        for (int k = tid; k < MD * S_SZ; k += 384) {
            wmu_s[(k >> 7) * WM_PITCH + (k & 127)] = f2bf(W_mu[k]);
            wlv_s[(k >> 7) * WM_PITCH + (k & 127)] = f2bf(W_lv[k]);
        }
        if (tid < S_SZ) hinf_s[tid] = h_inf[tid];
        __syncthreads();

        float lacc = 0.f;
        for (int s = 0; s < 32; ++s) {
            const int t = 1 + ls + 16 * s;
            if (t > T_LEN - 1) break;
            // wait for all 16 ct producer blocks of group lb to pass step t (magic-tagged)
            if (tid < 64) {
                while (true) {
                    bool ok = true;
                    if (tid < 16) {
                        unsigned cv = llc_load_u32(cnt + (lb + 8 * tid) * CNT_STRIDE);
                        ok = ((cv >> 16) == (CNT_MAGIC >> 16)) && ((cv & 0xFFFFu) >= (unsigned)t);
                    }
                    if (__ballot(ok) == ~0ull) break;
                    __builtin_amdgcn_s_sleep(64);
                }
            }
            __syncthreads();
            // stage hs tile (16 rows x 512 fp32) via LLC-coherent u64 loads
            const unsigned long long* hs64 =
                (const unsigned long long*)(hs + ((size_t)t * B_SZ + b0) * H_SZ);
            #pragma unroll
            for (int it = 0; it < 11; ++it) {
                const int c = tid + it * 384;
                if (c < 4096) {
                    const int m = c >> 8, q = c & 255;   // row, u64-in-row
                    unsigned long long v = llc_load_u64(hs64 + (size_t)m * 256 + q);
                    *(unsigned long long*)(hsT + m * HS_PITCH + q * 2) = v;
                }
            }
            __syncthreads();
            // phase 1: he = relu(W_he . h + b_he)
            if (tid < 256) {
                const int c = tid & 127, rg = tid >> 7;
                const float* __restrict__ wr = W_he + (size_t)c * H_SZ;
                float acc[8];
                #pragma unroll
                for (int ii = 0; ii < 8; ++ii) acc[ii] = b_he[c];
                for (int k = 0; k < H_SZ; k += 4) {
                    const float4 w4 = *(const float4*)(wr + k);
                    #pragma unroll
                    for (int ii = 0; ii < 8; ++ii) {
                        const float4 h4 = *(const float4*)(hsT + (rg * 8 + ii) * HS_PITCH + k);
                        acc[ii] = fmaf(w4.x, h4.x, acc[ii]);
                        acc[ii] = fmaf(w4.y, h4.y, acc[ii]);
                        acc[ii] = fmaf(w4.z, h4.z, acc[ii]);
                        acc[ii] = fmaf(w4.w, h4.w, acc[ii]);
                    }
                }
                #pragma unroll
                for (int ii = 0; ii < 8; ++ii)
                    he_s[(rg * 8 + ii) * 129 + c] = fmaxf(acc[ii], 0.f);
            }
            __syncthreads();
            // phase 2: markers + time LL
            if (tid < 256) {
                const int r = tid >> 4, q = tid & 15;
                const int row = t * B_SZ + b0 + r;
                const float mk = mask[row];
                #pragma unroll
                for (int pass = 0; pass < 2; ++pass) {
                    const int m = q + pass * 16;
                    if (m < MD) {
                        float mu = b_mu[m], lv = b_lv[m];
                        for (int c2 = 0; c2 < S_SZ; ++c2) {
                            const float h = he_s[r * 129 + c2];
                            mu = fmaf(h, bf2f(wmu_s[m * WM_PITCH + c2]), mu);
                            lv = fmaf(h, bf2f(wlv_s[m * WM_PITCH + c2]), lv);
                        }
                        const float lsg   = fmaxf(0.5f * lv, LOG001);
                        const float inv_s = __expf(-lsg);
                        const float zz    = (x[(size_t)row * MD + m] - mu) * inv_s;
                        lacc += (0.5f * zz * zz + lsg + HALF_L2PI) * mk;
                    }
                }
                if (q == 0) {
                    float past = 0.f;
                    for (int c2 = 0; c2 < S_SZ; ++c2)
                        past = fmaf(he_s[r * 129 + c2], hinf_s[c2], past);
                    const float ti = time_inf[0], bi = base_int[0];
                    const float dt = t_in[(size_t)row * 2 + 1];
                    const float term1 = past + ti * dt + bi;
                    const float tll = term1 + (__expf(past + bi) - __expf(term1)) / ti;
                    lacc += GAMMA_F * (-tll) * mk;
                }
            }
            __syncthreads();   // he_s/hsT reuse safety for next tile
        }
        // block reduce -> one atomic
        #pragma unroll
        for (int off = 32; off > 0; off >>= 1) lacc += __shfl_down(lacc, off, 64);
        if ((tid & 63) == 0) red[tid >> 6] = lacc;
        __syncthreads();
        if (tid == 0) {
            float sum = 0.f;
            #pragma unroll
            for (int w = 0; w < 6; ++w) sum += red[w];
            atomicAdd(out, sum);
        }
    }
}

extern "C" void kernel_launch(void* const* d_in, const int* in_sizes, int n_in,
                              void* d_out, int out_size, void* d_ws, size_t ws_size,
                              hipStream_t stream) {
    const float* x       = (const float*)d_in[0];
    const float* t_in    = (const float*)d_in[1];
    const float* mask    = (const float*)d_in[2];
    const float* W_embed = (const float*)d_in[3];
    const float* b_embed = (const float*)d_in[4];
    const float* W_ih    = (const float*)d_in[5];
    const float* b_ih    = (const float*)d_in[6];
    const float* W_hh    = (const float*)d_in[7];
    const float* b_hh    = (const float*)d_in[8];
    const float* W_he    = (const float*)d_in[9];
    const float* b_he    = (const float*)d_in[10];
    const float* W_mu    = (const float*)d_in[11];
    const float* b_mu    = (const float*)d_in[12];
    const float* W_lv    = (const float*)d_in[13];
    const float* b_lv    = (const float*)d_in[14];
    const float* h_inf   = (const float*)d_in[15];
    const float* tinf    = (const float*)d_in[16];
    const float* bint    = (const float*)d_in[17];
    float* out = (float*)d_out;

    // ws layout (bytes), 256-aligned: hs fp32 134.2M | hx 512K | cnt 8K
    char* ws = (char*)d_ws;
    const size_t OFF_HS  = 0;
    const size_t OFF_HX  = 134217728ull;
    const size_t OFF_CNT = 134742016ull;
    const size_t TOTAL   = 134750208ull;
    if (ws_size < TOTAL) return;
    float*    hsbuf = (float*)(ws + OFF_HS);
    unsigned* hx    = (unsigned*)(ws + OFF_HX);
    unsigned* cnt   = (unsigned*)(ws + OFF_CNT);

    void* args[] = {(void*)&W_ih, (void*)&W_hh, (void*)&hx, (void*)&hsbuf,
                    (void*)&b_ih, (void*)&b_hh, (void*)&cnt,
                    (void*)&W_embed, (void*)&b_embed,
                    (void*)&W_he, (void*)&b_he, (void*)&W_mu, (void*)&b_mu,
                    (void*)&W_lv, (void*)&b_lv, (void*)&h_inf, (void*)&tinf,
                    (void*)&bint, (void*)&x, (void*)&t_in, (void*)&mask, (void*)&out};
    hipLaunchCooperativeKernel((void*)fused_persist, dim3(256), dim3(384), args, 0, stream);
}

// Round 10
// 1905.637 us; speedup vs baseline: 1.4596x; 1.4596x over previous
//
#include <hip/hip_runtime.h>
#include <cstddef>
#include <cstdint>

// Model dims (fixed by reference)
#define T_LEN 512
#define B_SZ  128
#define MD    31
#define E_SZ  256
#define H_SZ  512
#define S_SZ  128
#define GAMMA_F 1.0f
#define LOG001   -4.605170185988091f   // log(0.01)
#define HALF_L2PI 0.9189385332046727f  // 0.5*log(2*pi)

typedef __attribute__((ext_vector_type(8))) short bf16x8;   // 8 bf16 in 4 VGPRs
typedef __attribute__((ext_vector_type(4))) float f32x4;

#define ACT_PITCH 536   // shorts: 512 + 24 pad
#define PHI_PITCH 264   // shorts: 256 + 8 pad
#define GP        36    // gate-array col pitch (floats)
#define HS_PITCH  516   // loss hs tile pitch (floats)
#define WM_PITCH  132   // loss wmu/wlv pitch (ushorts)
#define CNT_STRIDE 16   // dwords: one 64B line per counter
#define CNT_MAGIC  0x7E5A0000u   // high-16 marker: real counter vs 0xAA poison

// ---- shared-memory union (max of recurrence 43.3KB / loss 58.2KB) ----
#define SMEM_BYTES 58240
// recurrence offsets
#define R_ACT  0
#define R_PHI  17152
#define R_GS   34048
// loss offsets
#define L_HST  0
#define L_HES  33024
#define L_WMU  41280
#define L_WLV  49464
#define L_HINF 57648

__device__ inline unsigned short f2bf(float f) {   // fp32 -> bf16 bits, RNE
    union { float f; unsigned u; } v; v.f = f;
    unsigned r = v.u + 0x7FFFu + ((v.u >> 16) & 1u);
    return (unsigned short)(r >> 16);
}
__device__ inline float bf2f(unsigned short u) {
    union { unsigned u; float f; } v; v.u = (unsigned)u << 16; return v.f;
}
__device__ inline unsigned long long llc_load_u64(const unsigned long long* p) {
    return __hip_atomic_load(p, __ATOMIC_RELAXED, __HIP_MEMORY_SCOPE_AGENT);
}
__device__ inline unsigned llc_load_u32(const unsigned* p) {
    return __hip_atomic_load(p, __ATOMIC_RELAXED, __HIP_MEMORY_SCOPE_AGENT);
}

// ---------------- embed: phi_bf16[row][e] = bf16(relu(b_embed[e] + x[row]·W_embed[e])) -------
// Kept as a pre-kernel: R9 proved in-kernel embed lands on the recurrence critical path
// (−1150 µs regression); here it runs once at 1024-block parallelism (~40 µs, off-path).
__global__ __launch_bounds__(256) void embed_phi(
    const float* __restrict__ x, const float* __restrict__ W_embed,
    const float* __restrict__ b_embed, unsigned short* __restrict__ phi) {
    __shared__ float xs[8][32];
    const int e = threadIdx.x;
    float w[MD];
    #pragma unroll
    for (int m = 0; m < MD; ++m) w[m] = W_embed[e * MD + m];
    const float be = b_embed[e];
    const int nblocks = (T_LEN * B_SZ) / 8;
    for (int rb = blockIdx.x; rb < nblocks; rb += gridDim.x) {
        const int r0 = rb * 8;
        if (threadIdx.x < 8 * MD)
            xs[threadIdx.x / MD][threadIdx.x % MD] = x[(size_t)r0 * MD + threadIdx.x];
        __syncthreads();
        #pragma unroll
        for (int i = 0; i < 8; ++i) {
            float acc = be;
            #pragma unroll
            for (int m = 0; m < MD; ++m) acc = fmaf(xs[i][m], w[m], acc);
            phi[(size_t)(r0 + i) * E_SZ + e] = f2bf(fmaxf(acc, 0.f));
        }
        __syncthreads();
    }
}

// ---------------- fused persistent kernel: 128 recurrence blocks + 128 loss blocks ----------
// R8 loop structure (proven 1610 µs steady) + R9's proven-harmless init folds:
//  - weight fragments converted fp32->bf16 in registers at init (no pack_w / wpack)
//  - each recurrence block zeroes its own hx slot (no zero_init; tag-poll self-syncs)
//  - cnt magic-tagged (0xAA poison reads as not-ready); loss block 0 zeroes out[0]
__global__ __launch_bounds__(384) void fused_persist(
    const float* __restrict__ W_ih, const float* __restrict__ W_hh,
    const unsigned short* __restrict__ phi,
    unsigned* __restrict__ hx, float* __restrict__ hs,
    const float* __restrict__ b_ih, const float* __restrict__ b_hh,
    unsigned* __restrict__ cnt,
    const float* __restrict__ W_he, const float* __restrict__ b_he,
    const float* __restrict__ W_mu, const float* __restrict__ b_mu,
    const float* __restrict__ W_lv, const float* __restrict__ b_lv,
    const float* __restrict__ h_inf, const float* __restrict__ time_inf,
    const float* __restrict__ base_int, const float* __restrict__ x,
    const float* __restrict__ t_in, const float* __restrict__ mask,
    float* __restrict__ out) {
    __shared__ __align__(16) char smem[SMEM_BYTES];
    const int tid = threadIdx.x;

    if (blockIdx.x < 128) {
        // ================= RECURRENCE PATH =================
        short* act_s  = (short*)(smem + R_ACT);
        short* phi_s0 = (short*)(smem + R_PHI);
        short* phi_s1 = (short*)(smem + R_PHI) + 16 * PHI_PITCH;
        float* g_s    = (float*)(smem + R_GS);     // [4][16*GP]

        const int bt = blockIdx.x & 7, ct = blockIdx.x >> 3;
        const int b0 = bt * 16, j0 = ct * 32;
        const int wid = tid >> 6, L = tid & 63;
        const int gt = wid >> 1, ch = wid & 1;
        const int n_loc = L & 15, kb2 = L >> 4;
        const int a_row = L & 15;

        // --- zero own hx slot in buf0 (tag0 + h=0 == 0u); consumers retry until it lands ---
        {
            unsigned* own = hx + ((size_t)(0 * 8 + bt) * 16 + ct) * 512;
            __hip_atomic_store(own + tid, 0u, __ATOMIC_RELAXED, __HIP_MEMORY_SCOPE_AGENT);
            if (tid < 128)
                __hip_atomic_store(own + 384 + tid, 0u, __ATOMIC_RELAXED, __HIP_MEMORY_SCOPE_AGENT);
        }

        // --- convert loop-invariant B fragments fp32 -> bf16 in registers (one-time) ---
        const int col = gt * 512 + j0 + ch * 16 + n_loc;
        bf16x8 Bf[24];
        #pragma unroll
        for (int i = 0; i < 24; ++i) {
            const float* src = (i < 16)
                ? (W_hh + (size_t)col * H_SZ + i * 32 + kb2 * 8)
                : (W_ih + (size_t)col * E_SZ + (i - 16) * 32 + kb2 * 8);
            bf16x8 r;
            #pragma unroll
            for (int k = 0; k < 8; ++k) r[k] = (short)f2bf(src[k]);
            Bf[i] = r;
        }

        // gate-phase invariants (threads 0..255: cells (g_row,g_col),(g_row+8,g_col))
        const int g_row = tid >> 5, g_col = tid & 31;
        float bias_r = 0.f, bias_z = 0.f, bias_xn = 0.f, bias_hn = 0.f;
        if (tid < 256) {
            const int j = j0 + g_col;
            bias_r  = b_ih[j] + b_hh[j];
            bias_z  = b_ih[512 + j] + b_hh[512 + j];
            bias_xn = b_ih[1024 + j];
            bias_hn = b_hh[1024 + j];
        }
        float hold1 = 0.f, hold2 = 0.f;

        // prefetch phi t=0
        #pragma unroll
        for (int it = 0; it < 3; ++it) {
            const int c = tid + it * 384;
            if (c < 1024) {
                const int m = c >> 6, q = c & 63;
                *(unsigned long long*)(phi_s0 + m * PHI_PITCH + q * 4) =
                    *(const unsigned long long*)(phi + ((size_t)(b0 + m)) * E_SZ + q * 4);
            }
        }

        for (int t = 0; t < T_LEN - 1; ++t) {
            const int buf = t & 1;
            const short* phi_cur = buf ? phi_s1 : phi_s0;
            const unsigned tg = (unsigned)t & 0xFFFFu;

            // staging + implicit barrier: poll tagged h words (throttled retries)
            const unsigned long long* hx64 =
                (const unsigned long long*)hx + ((size_t)(buf * 8 + bt)) * 4096;
            unsigned long long v[11];
            #pragma unroll
            for (int it = 0; it < 11; ++it) {
                const int c = tid + it * 384;
                if (c < 4096) v[it] = llc_load_u64(hx64 + c);
            }
            while (true) {
                unsigned bad = 0;
                #pragma unroll
                for (int it = 0; it < 11; ++it) {
                    const int c = tid + it * 384;
                    if (c < 4096) {
                        const unsigned t0 = (unsigned)v[it] & 0xFFFFu;
                        const unsigned t1 = (unsigned)(v[it] >> 32) & 0xFFFFu;
                        if ((t0 ^ tg) | (t1 ^ tg)) bad |= (1u << it);
                    }
                }
                if (bad == 0) break;
                __builtin_amdgcn_s_sleep(1);   // throttle spin traffic at the LLC
                #pragma unroll
                for (int it = 0; it < 11; ++it)
                    if (bad & (1u << it)) v[it] = llc_load_u64(hx64 + tid + it * 384);
            }
            #pragma unroll
            for (int it = 0; it < 11; ++it) {
                const int c = tid + it * 384;
                if (c < 4096) {
                    const int ctp = c >> 8, w = c & 255, row = w >> 4, colp = w & 15;
                    const unsigned lo = (unsigned)(v[it] >> 16) & 0xFFFFu;
                    const unsigned hi = (unsigned)(v[it] >> 48) & 0xFFFFu;
                    *(unsigned*)(act_s + row * ACT_PITCH + ctp * 32 + colp * 2) = lo | (hi << 16);
                }
            }
            __syncthreads();
            // publish: hs rows <= t are at LLC (drained by the sync above)
            if (tid == 0 && t)
                __hip_atomic_store(cnt + blockIdx.x * CNT_STRIDE, CNT_MAGIC | tg,
                                   __ATOMIC_RELAXED, __HIP_MEMORY_SCOPE_AGENT);

            // next phi prefetch (held in regs)
            unsigned long long pv[3];
            const int tn = t + 1;
            if (tn < T_LEN - 1) {
                #pragma unroll
                for (int it = 0; it < 3; ++it) {
                    const int c = tid + it * 384;
                    if (c < 1024) {
                        const int m = c >> 6, q = c & 63;
                        pv[it] = *(const unsigned long long*)(
                            phi + ((size_t)tn * B_SZ + b0 + m) * E_SZ + q * 4);
                    }
                }
            }

            // MFMA: split accumulate chains (even/odd k-blocks)
            {
                const short* arow = act_s + a_row * ACT_PITCH;
                const short* prow = phi_cur + a_row * PHI_PITCH;
                f32x4 acc0 = {0.f, 0.f, 0.f, 0.f};
                f32x4 acc1 = {0.f, 0.f, 0.f, 0.f};
                #pragma unroll
                for (int i = 0; i < 16; i += 2) {
                    bf16x8 a0 = *(const bf16x8*)(arow + i * 32 + kb2 * 8);
                    bf16x8 a1 = *(const bf16x8*)(arow + (i + 1) * 32 + kb2 * 8);
                    acc0 = __builtin_amdgcn_mfma_f32_16x16x32_bf16(a0, Bf[i], acc0, 0, 0, 0);
                    acc1 = __builtin_amdgcn_mfma_f32_16x16x32_bf16(a1, Bf[i + 1], acc1, 0, 0, 0);
                }
                if (gt < 2) {
                    #pragma unroll
                    for (int i = 16; i < 24; i += 2) {
                        bf16x8 a0 = *(const bf16x8*)(prow + (i - 16) * 32 + kb2 * 8);
                        bf16x8 a1 = *(const bf16x8*)(prow + (i - 15) * 32 + kb2 * 8);
                        acc0 = __builtin_amdgcn_mfma_f32_16x16x32_bf16(a0, Bf[i], acc0, 0, 0, 0);
                        acc1 = __builtin_amdgcn_mfma_f32_16x16x32_bf16(a1, Bf[i + 1], acc1, 0, 0, 0);
                    }
                    #pragma unroll
                    for (int i2 = 0; i2 < 4; ++i2)
                        g_s[gt * 16 * GP + ((L >> 4) * 4 + i2) * GP + ch * 16 + n_loc] =
                            acc0[i2] + acc1[i2];
                } else {
                    f32x4 accB = {0.f, 0.f, 0.f, 0.f};
                    #pragma unroll
                    for (int i = 16; i < 24; ++i) {
                        bf16x8 a = *(const bf16x8*)(prow + (i - 16) * 32 + kb2 * 8);
                        accB = __builtin_amdgcn_mfma_f32_16x16x32_bf16(a, Bf[i], accB, 0, 0, 0);
                    }
                    #pragma unroll
                    for (int i2 = 0; i2 < 4; ++i2) {
                        const int idx = ((L >> 4) * 4 + i2) * GP + ch * 16 + n_loc;
                        g_s[2 * 16 * GP + idx] = acc0[i2] + acc1[i2];   // hn
                        g_s[3 * 16 * GP + idx] = accB[i2];              // xn
                    }
                }
            }

            // commit prefetched phi
            if (tn < T_LEN - 1) {
                short* pbuf = (tn & 1) ? phi_s1 : phi_s0;
                #pragma unroll
                for (int it = 0; it < 3; ++it) {
                    const int c = tid + it * 384;
                    if (c < 1024) {
                        const int m = c >> 6, q = c & 63;
                        *(unsigned long long*)(pbuf + m * PHI_PITCH + q * 4) = pv[it];
                    }
                }
            }
            __syncthreads();

            // gate math + state update + tagged store
            if (tid < 256) {
                const int nb = (t + 1) & 1;
                unsigned* hxdst = hx + ((size_t)(nb * 8 + bt) * 16 + ct) * 512;
                #pragma unroll
                for (int half = 0; half < 2; ++half) {
                    const int row = g_row + half * 8;
                    const int idx = row * GP + g_col;
                    float& hold = half ? hold2 : hold1;
                    const float pre_r = g_s[0 * 16 * GP + idx] + bias_r;
                    const float pre_z = g_s[1 * 16 * GP + idx] + bias_z;
                    const float hn    = g_s[2 * 16 * GP + idx] + bias_hn;
                    const float xn    = g_s[3 * 16 * GP + idx] + bias_xn;
                    const float r = 1.f / (1.f + __expf(-pre_r));
                    const float z = 1.f / (1.f + __expf(-pre_z));
                    const float e2 = __expf(-2.f * fmaf(r, hn, xn));
                    const float n = (1.f - e2) / (1.f + e2);          // tanh
                    const float hnew = fmaf(z, hold - n, n);          // (1-z)*n + z*h
                    hold = hnew;
                    __hip_atomic_store(
                        hs + (size_t)(t + 1) * B_SZ * H_SZ + (size_t)(b0 + row) * H_SZ + j0 + g_col,
                        hnew, __ATOMIC_RELAXED, __HIP_MEMORY_SCOPE_AGENT);
                    if (t < T_LEN - 2)
                        __hip_atomic_store(hxdst + row * 32 + g_col,
                                           ((unsigned)f2bf(hnew) << 16) | ((unsigned)(t + 1) & 0xFFFFu),
                                           __ATOMIC_RELAXED, __HIP_MEMORY_SCOPE_AGENT);
                }
            }
        }
        __syncthreads();   // drain final hs stores
        if (tid == 0)
            __hip_atomic_store(cnt + blockIdx.x * CNT_STRIDE, CNT_MAGIC | (unsigned)(T_LEN - 1),
                               __ATOMIC_RELAXED, __HIP_MEMORY_SCOPE_AGENT);
    } else {
        // ================= LOSS PATH =================
        float* hsT  = (float*)(smem + L_HST);            // [16][HS_PITCH]
        float* he_s = (float*)(smem + L_HES);            // [16][129]
        unsigned short* wmu_s = (unsigned short*)(smem + L_WMU);  // [31][WM_PITCH] bf16
        unsigned short* wlv_s = (unsigned short*)(smem + L_WLV);
        float* hinf_s = (float*)(smem + L_HINF);         // [128]
        float* red    = (float*)(smem + L_HINF) + 128;   // [6]

        const int i = blockIdx.x - 128;
        const int lb = i & 7, ls = i >> 3;
        const int b0 = lb * 16;

        if (i == 0 && tid == 0)     // zero the output; adds are cnt-gated much later
            __hip_atomic_store(out, 0.f, __ATOMIC_RELAXED, __HIP_MEMORY_SCOPE_AGENT);

        for (int k = tid; k < MD * S_SZ; k += 384) {
            wmu_s[(k >> 7) * WM_PITCH + (k & 127)] = f2bf(W_mu[k]);
            wlv_s[(k >> 7) * WM_PITCH + (k & 127)] = f2bf(W_lv[k]);
        }
        if (tid < S_SZ) hinf_s[tid] = h_inf[tid];
        __syncthreads();

        float lacc = 0.f;
        for (int s = 0; s < 32; ++s) {
            const int t = 1 + ls + 16 * s;
            if (t > T_LEN - 1) break;
            // wait for all 16 ct producer blocks of group lb to pass step t (magic-tagged)
            if (tid < 64) {
                while (true) {
                    bool ok = true;
                    if (tid < 16) {
                        unsigned cv = llc_load_u32(cnt + (lb + 8 * tid) * CNT_STRIDE);
                        ok = ((cv >> 16) == (CNT_MAGIC >> 16)) && ((cv & 0xFFFFu) >= (unsigned)t);
                    }
                    if (__ballot(ok) == ~0ull) break;
                    __builtin_amdgcn_s_sleep(64);
                }
            }
            __syncthreads();
            // stage hs tile (16 rows x 512 fp32) via LLC-coherent u64 loads
            const unsigned long long* hs64 =
                (const unsigned long long*)(hs + ((size_t)t * B_SZ + b0) * H_SZ);
            #pragma unroll
            for (int it = 0; it < 11; ++it) {
                const int c = tid + it * 384;
                if (c < 4096) {
                    const int m = c >> 8, q = c & 255;   // row, u64-in-row
                    unsigned long long v = llc_load_u64(hs64 + (size_t)m * 256 + q);
                    *(unsigned long long*)(hsT + m * HS_PITCH + q * 2) = v;
                }
            }
            __syncthreads();
            // phase 1: he = relu(W_he . h + b_he)
            if (tid < 256) {
                const int c = tid & 127, rg = tid >> 7;
                const float* __restrict__ wr = W_he + (size_t)c * H_SZ;
                float acc[8];
                #pragma unroll
                for (int ii = 0; ii < 8; ++ii) acc[ii] = b_he[c];
                for (int k = 0; k < H_SZ; k += 4) {
                    const float4 w4 = *(const float4*)(wr + k);
                    #pragma unroll
                    for (int ii = 0; ii < 8; ++ii) {
                        const float4 h4 = *(const float4*)(hsT + (rg * 8 + ii) * HS_PITCH + k);
                        acc[ii] = fmaf(w4.x, h4.x, acc[ii]);
                        acc[ii] = fmaf(w4.y, h4.y, acc[ii]);
                        acc[ii] = fmaf(w4.z, h4.z, acc[ii]);
                        acc[ii] = fmaf(w4.w, h4.w, acc[ii]);
                    }
                }
                #pragma unroll
                for (int ii = 0; ii < 8; ++ii)
                    he_s[(rg * 8 + ii) * 129 + c] = fmaxf(acc[ii], 0.f);
            }
            __syncthreads();
            // phase 2: markers + time LL
            if (tid < 256) {
                const int r = tid >> 4, q = tid & 15;
                const int row = t * B_SZ + b0 + r;
                const float mk = mask[row];
                #pragma unroll
                for (int pass = 0; pass < 2; ++pass) {
                    const int m = q + pass * 16;
                    if (m < MD) {
                        float mu = b_mu[m], lv = b_lv[m];
                        for (int c2 = 0; c2 < S_SZ; ++c2) {
                            const float h = he_s[r * 129 + c2];
                            mu = fmaf(h, bf2f(wmu_s[m * WM_PITCH + c2]), mu);
                            lv = fmaf(h, bf2f(wlv_s[m * WM_PITCH + c2]), lv);
                        }
                        const float lsg   = fmaxf(0.5f * lv, LOG001);
                        const float inv_s = __expf(-lsg);
                        const float zz    = (x[(size_t)row * MD + m] - mu) * inv_s;
                        lacc += (0.5f * zz * zz + lsg + HALF_L2PI) * mk;
                    }
                }
                if (q == 0) {
                    float past = 0.f;
                    for (int c2 = 0; c2 < S_SZ; ++c2)
                        past = fmaf(he_s[r * 129 + c2], hinf_s[c2], past);
                    const float ti = time_inf[0], bi = base_int[0];
                    const float dt = t_in[(size_t)row * 2 + 1];
                    const float term1 = past + ti * dt + bi;
                    const float tll = term1 + (__expf(past + bi) - __expf(term1)) / ti;
                    lacc += GAMMA_F * (-tll) * mk;
                }
            }
            __syncthreads();   // he_s/hsT reuse safety for next tile
        }
        // block reduce -> one atomic
        #pragma unroll
        for (int off = 32; off > 0; off >>= 1) lacc += __shfl_down(lacc, off, 64);
        if ((tid & 63) == 0) red[tid >> 6] = lacc;
        __syncthreads();
        if (tid == 0) {
            float sum = 0.f;
            #pragma unroll
            for (int w = 0; w < 6; ++w) sum += red[w];
            atomicAdd(out, sum);
        }
    }
}

extern "C" void kernel_launch(void* const* d_in, const int* in_sizes, int n_in,
                              void* d_out, int out_size, void* d_ws, size_t ws_size,
                              hipStream_t stream) {
    const float* x       = (const float*)d_in[0];
    const float* t_in    = (const float*)d_in[1];
    const float* mask    = (const float*)d_in[2];
    const float* W_embed = (const float*)d_in[3];
    const float* b_embed = (const float*)d_in[4];
    const float* W_ih    = (const float*)d_in[5];
    const float* b_ih    = (const float*)d_in[6];
    const float* W_hh    = (const float*)d_in[7];
    const float* b_hh    = (const float*)d_in[8];
    const float* W_he    = (const float*)d_in[9];
    const float* b_he    = (const float*)d_in[10];
    const float* W_mu    = (const float*)d_in[11];
    const float* b_mu    = (const float*)d_in[12];
    const float* W_lv    = (const float*)d_in[13];
    const float* b_lv    = (const float*)d_in[14];
    const float* h_inf   = (const float*)d_in[15];
    const float* tinf    = (const float*)d_in[16];
    const float* bint    = (const float*)d_in[17];
    float* out = (float*)d_out;

    // ws layout (bytes), 256-aligned: phi_bf16 33.5M | hs fp32 134.2M | hx 512K | cnt 8K
    char* ws = (char*)d_ws;
    const size_t OFF_PHI = 0;
    const size_t OFF_HS  = 33554432ull;
    const size_t OFF_HX  = 167772160ull;
    const size_t OFF_CNT = 168296448ull;
    const size_t TOTAL   = 168304640ull;
    if (ws_size < TOTAL) return;
    unsigned short* phi   = (unsigned short*)(ws + OFF_PHI);
    float*          hsbuf = (float*)(ws + OFF_HS);
    unsigned*       hx    = (unsigned*)(ws + OFF_HX);
    unsigned*       cnt   = (unsigned*)(ws + OFF_CNT);

    embed_phi<<<dim3(1024), 256, 0, stream>>>(x, W_embed, b_embed, phi);

    void* args[] = {(void*)&W_ih, (void*)&W_hh, (void*)&phi, (void*)&hx, (void*)&hsbuf,
                    (void*)&b_ih, (void*)&b_hh, (void*)&cnt,
                    (void*)&W_he, (void*)&b_he, (void*)&W_mu, (void*)&b_mu,
                    (void*)&W_lv, (void*)&b_lv, (void*)&h_inf, (void*)&tinf,
                    (void*)&bint, (void*)&x, (void*)&t_in, (void*)&mask, (void*)&out};
    hipLaunchCooperativeKernel((void*)fused_persist, dim3(256), dim3(384), args, 0, stream);
}

// Round 11
// 1708.144 us; speedup vs baseline: 1.6284x; 1.1156x over previous
//
#include <hip/hip_runtime.h>
#include <cstddef>
#include <cstdint>

// Model dims (fixed by reference)
#define T_LEN 512
#define B_SZ  128
#define MD    31
#define E_SZ  256
#define H_SZ  512
#define S_SZ  128
#define GAMMA_F 1.0f
#define LOG001   -4.605170185988091f   // log(0.01)
#define HALF_L2PI 0.9189385332046727f  // 0.5*log(2*pi)

typedef __attribute__((ext_vector_type(8))) short bf16x8;   // 8 bf16 in 4 VGPRs
typedef __attribute__((ext_vector_type(4))) float f32x4;

#define ACT_PITCH 536   // shorts: 512 + 24 pad
#define PHI_PITCH 264   // shorts: 256 + 8 pad
#define GP        36    // gate-array col pitch (floats)
#define HS_PITCH  516   // loss hs tile pitch (floats)
#define WM_PITCH  132   // loss wmu/wlv pitch (ushorts)
#define CNT_STRIDE 16   // dwords: one 64B line per counter (de-hotspot)

// ---- shared-memory union (max of recurrence 43.3KB / loss 58.2KB) ----
#define SMEM_BYTES 58240
// recurrence offsets
#define R_ACT  0
#define R_PHI  17152
#define R_GS   34048
// loss offsets
#define L_HST  0
#define L_HES  33024
#define L_WMU  41280
#define L_WLV  49464
#define L_HINF 57648

__device__ inline unsigned short f2bf(float f) {   // fp32 -> bf16 bits, RNE
    union { float f; unsigned u; } v; v.f = f;
    unsigned r = v.u + 0x7FFFu + ((v.u >> 16) & 1u);
    return (unsigned short)(r >> 16);
}
__device__ inline float bf2f(unsigned short u) {
    union { unsigned u; float f; } v; v.u = (unsigned)u << 16; return v.f;
}
__device__ inline unsigned long long llc_load_u64(const unsigned long long* p) {
    return __hip_atomic_load(p, __ATOMIC_RELAXED, __HIP_MEMORY_SCOPE_AGENT);
}
__device__ inline unsigned llc_load_u32(const unsigned* p) {
    return __hip_atomic_load(p, __ATOMIC_RELAXED, __HIP_MEMORY_SCOPE_AGENT);
}

// ---------------- single prep kernel: pack_w + embed_phi + zero(hx buf0, cnt, out) ----------
// blocks 0..511: pack weights (first 64 also zero hx buf0; block 0 zeros cnt+out)
// blocks 512..1535: embed (identical math to the proven embed_phi)
__global__ __launch_bounds__(256) void prep(
    const float* __restrict__ x, const float* __restrict__ W_embed,
    const float* __restrict__ b_embed,
    const float* __restrict__ W_ih, const float* __restrict__ W_hh,
    unsigned short* __restrict__ wpack, unsigned short* __restrict__ phi,
    unsigned* __restrict__ hx, unsigned* __restrict__ cnt, float* __restrict__ out) {
    const int blk = blockIdx.x;
    if (blk < 512) {
        // ---- pack W -> bf16: wpack[col][768] = [W_hh[col][0:512] | W_ih[col][0:256]] ----
        const int n = 1536 * 768;
        for (int i = blk * 256 + threadIdx.x; i < n; i += 512 * 256) {
            int col = i / 768, k = i - col * 768;
            float v = (k < H_SZ) ? W_hh[col * H_SZ + k] : W_ih[col * E_SZ + (k - H_SZ)];
            wpack[i] = f2bf(v);
        }
        if (blk < 64) {            // zero hx buf0: 65536 u32 over 64 blocks
            #pragma unroll
            for (int k = 0; k < 4; ++k) hx[blk * 1024 + k * 256 + threadIdx.x] = 0u;
        }
        if (blk == 0) {            // zero cnt (128*CNT_STRIDE u32) + out
            for (int k = threadIdx.x; k < 128 * CNT_STRIDE; k += 256) cnt[k] = 0u;
            if (threadIdx.x == 0) out[0] = 0.f;
        }
    } else {
        // ---- embed: phi[row][e] = bf16(relu(b_embed[e] + x[row]·W_embed[e])) ----
        __shared__ float xs[8][32];
        const int e = threadIdx.x;
        float w[MD];
        #pragma unroll
        for (int m = 0; m < MD; ++m) w[m] = W_embed[e * MD + m];
        const float be = b_embed[e];
        const int nblocks = (T_LEN * B_SZ) / 8;
        for (int rb = blk - 512; rb < nblocks; rb += 1024) {
            const int r0 = rb * 8;
            if (threadIdx.x < 8 * MD)
                xs[threadIdx.x / MD][threadIdx.x % MD] = x[(size_t)r0 * MD + threadIdx.x];
            __syncthreads();
            #pragma unroll
            for (int i = 0; i < 8; ++i) {
                float acc = be;
                #pragma unroll
                for (int m = 0; m < MD; ++m) acc = fmaf(xs[i][m], w[m], acc);
                phi[(size_t)(r0 + i) * E_SZ + e] = f2bf(fmaxf(acc, 0.f));
            }
            __syncthreads();
        }
    }
}

// ---------------- fused persistent kernel: 128 recurrence blocks + 128 loss blocks ----------
// EXACT R8 structure (proven 1610 µs steady, VGPR 100). R9/R10 showed any extra in-kernel
// init (weight conversion, embed) regresses the steady state via register pressure.
__global__ __launch_bounds__(384) void fused_persist(
    const unsigned short* __restrict__ wpack, const unsigned short* __restrict__ phi,
    unsigned* __restrict__ hx, float* __restrict__ hs,
    const float* __restrict__ b_ih, const float* __restrict__ b_hh,
    unsigned* __restrict__ cnt,
    const float* __restrict__ W_he, const float* __restrict__ b_he,
    const float* __restrict__ W_mu, const float* __restrict__ b_mu,
    const float* __restrict__ W_lv, const float* __restrict__ b_lv,
    const float* __restrict__ h_inf, const float* __restrict__ time_inf,
    const float* __restrict__ base_int, const float* __restrict__ x,
    const float* __restrict__ t_in, const float* __restrict__ mask,
    float* __restrict__ out) {
    __shared__ __align__(16) char smem[SMEM_BYTES];
    const int tid = threadIdx.x;

    if (blockIdx.x < 128) {
        // ================= RECURRENCE PATH =================
        short* act_s = (short*)(smem + R_ACT);
        short* phi_s0 = (short*)(smem + R_PHI);
        short* phi_s1 = (short*)(smem + R_PHI) + 16 * PHI_PITCH;
        float* g_s = (float*)(smem + R_GS);     // [4][16*GP]

        const int bt = blockIdx.x & 7, ct = blockIdx.x >> 3;
        const int b0 = bt * 16, j0 = ct * 32;
        const int wid = tid >> 6, L = tid & 63;
        const int gt = wid >> 1, ch = wid & 1;
        const int n_loc = L & 15, kb2 = L >> 4;
        const int a_row = L & 15;

        const unsigned short* __restrict__ wrow =
            wpack + (size_t)(gt * 512 + j0 + ch * 16 + n_loc) * 768;
        bf16x8 Bf[24];
        #pragma unroll
        for (int i = 0; i < 24; ++i) Bf[i] = *(const bf16x8*)(wrow + i * 32 + kb2 * 8);

        const int g_row = tid >> 5, g_col = tid & 31;
        float bias_r = 0.f, bias_z = 0.f, bias_xn = 0.f, bias_hn = 0.f;
        if (tid < 256) {
            const int j = j0 + g_col;
            bias_r  = b_ih[j] + b_hh[j];
            bias_z  = b_ih[512 + j] + b_hh[512 + j];
            bias_xn = b_ih[1024 + j];
            bias_hn = b_hh[1024 + j];
        }
        float hold1 = 0.f, hold2 = 0.f;

        // prefetch phi t=0
        #pragma unroll
        for (int it = 0; it < 3; ++it) {
            const int c = tid + it * 384;
            if (c < 1024) {
                const int m = c >> 6, q = c & 63;
                *(unsigned long long*)(phi_s0 + m * PHI_PITCH + q * 4) =
                    *(const unsigned long long*)(phi + ((size_t)(b0 + m)) * E_SZ + q * 4);
            }
        }

        for (int t = 0; t < T_LEN - 1; ++t) {
            const int buf = t & 1;
            const short* phi_cur = buf ? phi_s1 : phi_s0;
            const unsigned tg = (unsigned)t & 0xFFFFu;

            // staging + implicit barrier: poll tagged h words (throttled retries)
            const unsigned long long* hx64 =
                (const unsigned long long*)hx + ((size_t)(buf * 8 + bt)) * 4096;
            unsigned long long v[11];
            #pragma unroll
            for (int it = 0; it < 11; ++it) {
                const int c = tid + it * 384;
                if (c < 4096) v[it] = llc_load_u64(hx64 + c);
            }
            while (true) {
                unsigned bad = 0;
                #pragma unroll
                for (int it = 0; it < 11; ++it) {
                    const int c = tid + it * 384;
                    if (c < 4096) {
                        const unsigned t0 = (unsigned)v[it] & 0xFFFFu;
                        const unsigned t1 = (unsigned)(v[it] >> 32) & 0xFFFFu;
                        if ((t0 ^ tg) | (t1 ^ tg)) bad |= (1u << it);
                    }
                }
                if (bad == 0) break;
                __builtin_amdgcn_s_sleep(1);   // throttle spin traffic at the LLC
                #pragma unroll
                for (int it = 0; it < 11; ++it)
                    if (bad & (1u << it)) v[it] = llc_load_u64(hx64 + tid + it * 384);
            }
            #pragma unroll
            for (int it = 0; it < 11; ++it) {
                const int c = tid + it * 384;
                if (c < 4096) {
                    const int ctp = c >> 8, w = c & 255, row = w >> 4, colp = w & 15;
                    const unsigned lo = (unsigned)(v[it] >> 16) & 0xFFFFu;
                    const unsigned hi = (unsigned)(v[it] >> 48) & 0xFFFFu;
                    *(unsigned*)(act_s + row * ACT_PITCH + ctp * 32 + colp * 2) = lo | (hi << 16);
                }
            }
            __syncthreads();
            // publish: hs rows <= t are at LLC (drained by the sync above)
            if (tid == 0 && t)
                __hip_atomic_store(cnt + blockIdx.x * CNT_STRIDE, (unsigned)t,
                                   __ATOMIC_RELAXED, __HIP_MEMORY_SCOPE_AGENT);

            // next phi prefetch (held in regs)
            unsigned long long pv[3];
            const int tn = t + 1;
            if (tn < T_LEN - 1) {
                #pragma unroll
                for (int it = 0; it < 3; ++it) {
                    const int c = tid + it * 384;
                    if (c < 1024) {
                        const int m = c >> 6, q = c & 63;
                        pv[it] = *(const unsigned long long*)(
                            phi + ((size_t)tn * B_SZ + b0 + m) * E_SZ + q * 4);
                    }
                }
            }

            // MFMA: split accumulate chains (even/odd k-blocks)
            {
                const short* arow = act_s + a_row * ACT_PITCH;
                const short* prow = phi_cur + a_row * PHI_PITCH;
                f32x4 acc0 = {0.f, 0.f, 0.f, 0.f};
                f32x4 acc1 = {0.f, 0.f, 0.f, 0.f};
                #pragma unroll
                for (int i = 0; i < 16; i += 2) {
                    bf16x8 a0 = *(const bf16x8*)(arow + i * 32 + kb2 * 8);
                    bf16x8 a1 = *(const bf16x8*)(arow + (i + 1) * 32 + kb2 * 8);
                    acc0 = __builtin_amdgcn_mfma_f32_16x16x32_bf16(a0, Bf[i], acc0, 0, 0, 0);
                    acc1 = __builtin_amdgcn_mfma_f32_16x16x32_bf16(a1, Bf[i + 1], acc1, 0, 0, 0);
                }
                if (gt < 2) {
                    #pragma unroll
                    for (int i = 16; i < 24; i += 2) {
                        bf16x8 a0 = *(const bf16x8*)(prow + (i - 16) * 32 + kb2 * 8);
                        bf16x8 a1 = *(const bf16x8*)(prow + (i - 15) * 32 + kb2 * 8);
                        acc0 = __builtin_amdgcn_mfma_f32_16x16x32_bf16(a0, Bf[i], acc0, 0, 0, 0);
                        acc1 = __builtin_amdgcn_mfma_f32_16x16x32_bf16(a1, Bf[i + 1], acc1, 0, 0, 0);
                    }
                    #pragma unroll
                    for (int i2 = 0; i2 < 4; ++i2)
                        g_s[gt * 16 * GP + ((L >> 4) * 4 + i2) * GP + ch * 16 + n_loc] =
                            acc0[i2] + acc1[i2];
                } else {
                    f32x4 accB = {0.f, 0.f, 0.f, 0.f};
                    #pragma unroll
                    for (int i = 16; i < 24; ++i) {
                        bf16x8 a = *(const bf16x8*)(prow + (i - 16) * 32 + kb2 * 8);
                        accB = __builtin_amdgcn_mfma_f32_16x16x32_bf16(a, Bf[i], accB, 0, 0, 0);
                    }
                    #pragma unroll
                    for (int i2 = 0; i2 < 4; ++i2) {
                        const int idx = ((L >> 4) * 4 + i2) * GP + ch * 16 + n_loc;
                        g_s[2 * 16 * GP + idx] = acc0[i2] + acc1[i2];   // hn
                        g_s[3 * 16 * GP + idx] = accB[i2];              // xn
                    }
                }
            }

            // commit prefetched phi
            if (tn < T_LEN - 1) {
                short* pbuf = (tn & 1) ? phi_s1 : phi_s0;
                #pragma unroll
                for (int it = 0; it < 3; ++it) {
                    const int c = tid + it * 384;
                    if (c < 1024) {
                        const int m = c >> 6, q = c & 63;
                        *(unsigned long long*)(pbuf + m * PHI_PITCH + q * 4) = pv[it];
                    }
                }
            }
            __syncthreads();

            // gate math + state update + tagged store
            if (tid < 256) {
                const int nb = (t + 1) & 1;
                unsigned* hxdst = hx + ((size_t)(nb * 8 + bt) * 16 + ct) * 512;
                #pragma unroll
                for (int half = 0; half < 2; ++half) {
                    const int row = g_row + half * 8;
                    const int idx = row * GP + g_col;
                    float& hold = half ? hold2 : hold1;
                    const float pre_r = g_s[0 * 16 * GP + idx] + bias_r;
                    const float pre_z = g_s[1 * 16 * GP + idx] + bias_z;
                    const float hn    = g_s[2 * 16 * GP + idx] + bias_hn;
                    const float xn    = g_s[3 * 16 * GP + idx] + bias_xn;
                    const float r = 1.f / (1.f + __expf(-pre_r));
                    const float z = 1.f / (1.f + __expf(-pre_z));
                    const float e2 = __expf(-2.f * fmaf(r, hn, xn));
                    const float n = (1.f - e2) / (1.f + e2);          // tanh
                    const float hnew = fmaf(z, hold - n, n);          // (1-z)*n + z*h
                    hold = hnew;
                    __hip_atomic_store(
                        hs + (size_t)(t + 1) * B_SZ * H_SZ + (size_t)(b0 + row) * H_SZ + j0 + g_col,
                        hnew, __ATOMIC_RELAXED, __HIP_MEMORY_SCOPE_AGENT);
                    if (t < T_LEN - 2)
                        __hip_atomic_store(hxdst + row * 32 + g_col,
                                           ((unsigned)f2bf(hnew) << 16) | ((unsigned)(t + 1) & 0xFFFFu),
                                           __ATOMIC_RELAXED, __HIP_MEMORY_SCOPE_AGENT);
                }
            }
        }
        __syncthreads();   // drain final hs stores
        if (tid == 0)
            __hip_atomic_store(cnt + blockIdx.x * CNT_STRIDE, (unsigned)(T_LEN - 1),
                               __ATOMIC_RELAXED, __HIP_MEMORY_SCOPE_AGENT);
    } else {
        // ================= LOSS PATH =================
        float* hsT  = (float*)(smem + L_HST);            // [16][HS_PITCH]
        float* he_s = (float*)(smem + L_HES);            // [16][129]
        unsigned short* wmu_s = (unsigned short*)(smem + L_WMU);  // [31][WM_PITCH] bf16
        unsigned short* wlv_s = (unsigned short*)(smem + L_WLV);
        float* hinf_s = (float*)(smem + L_HINF);         // [128]
        float* red    = (float*)(smem + L_HINF) + 128;   // [6]

        const int i = blockIdx.x - 128;
        const int lb = i & 7, ls = i >> 3;
        const int b0 = lb * 16;

        for (int k = tid; k < MD * S_SZ; k += 384) {
            wmu_s[(k >> 7) * WM_PITCH + (k & 127)] = f2bf(W_mu[k]);
            wlv_s[(k >> 7) * WM_PITCH + (k & 127)] = f2bf(W_lv[k]);
        }
        if (tid < S_SZ) hinf_s[tid] = h_inf[tid];
        __syncthreads();

        float lacc = 0.f;
        for (int s = 0; s < 32; ++s) {
            const int t = 1 + ls + 16 * s;
            if (t > T_LEN - 1) break;
            // wait for all 16 ct producer blocks of group lb to pass step t
            if (tid < 64) {
                while (true) {
                    unsigned cv = 0xFFFFFFFFu;
                    if (tid < 16) cv = llc_load_u32(cnt + (lb + 8 * tid) * CNT_STRIDE);
                    if (__ballot(cv >= (unsigned)t) == ~0ull) break;
                    __builtin_amdgcn_s_sleep(64);
                }
            }
            __syncthreads();
            // stage hs tile (16 rows x 512 fp32) via LLC-coherent u64 loads
            const unsigned long long* hs64 =
                (const unsigned long long*)(hs + ((size_t)t * B_SZ + b0) * H_SZ);
            #pragma unroll
            for (int it = 0; it < 11; ++it) {
                const int c = tid + it * 384;
                if (c < 4096) {
                    const int m = c >> 8, q = c & 255;   // row, u64-in-row
                    unsigned long long v = llc_load_u64(hs64 + (size_t)m * 256 + q);
                    *(unsigned long long*)(hsT + m * HS_PITCH + q * 2) = v;
                }
            }
            __syncthreads();
            // phase 1: he = relu(W_he . h + b_he)
            if (tid < 256) {
                const int c = tid & 127, rg = tid >> 7;
                const float* __restrict__ wr = W_he + (size_t)c * H_SZ;
                float acc[8];
                #pragma unroll
                for (int ii = 0; ii < 8; ++ii) acc[ii] = b_he[c];
                for (int k = 0; k < H_SZ; k += 4) {
                    const float4 w4 = *(const float4*)(wr + k);
                    #pragma unroll
                    for (int ii = 0; ii < 8; ++ii) {
                        const float4 h4 = *(const float4*)(hsT + (rg * 8 + ii) * HS_PITCH + k);
                        acc[ii] = fmaf(w4.x, h4.x, acc[ii]);
                        acc[ii] = fmaf(w4.y, h4.y, acc[ii]);
                        acc[ii] = fmaf(w4.z, h4.z, acc[ii]);
                        acc[ii] = fmaf(w4.w, h4.w, acc[ii]);
                    }
                }
                #pragma unroll
                for (int ii = 0; ii < 8; ++ii)
                    he_s[(rg * 8 + ii) * 129 + c] = fmaxf(acc[ii], 0.f);
            }
            __syncthreads();
            // phase 2: markers + time LL
            if (tid < 256) {
                const int r = tid >> 4, q = tid & 15;
                const int row = t * B_SZ + b0 + r;
                const float mk = mask[row];
                #pragma unroll
                for (int pass = 0; pass < 2; ++pass) {
                    const int m = q + pass * 16;
                    if (m < MD) {
                        float mu = b_mu[m], lv = b_lv[m];
                        for (int c2 = 0; c2 < S_SZ; ++c2) {
                            const float h = he_s[r * 129 + c2];
                            mu = fmaf(h, bf2f(wmu_s[m * WM_PITCH + c2]), mu);
                            lv = fmaf(h, bf2f(wlv_s[m * WM_PITCH + c2]), lv);
                        }
                        const float lsg   = fmaxf(0.5f * lv, LOG001);
                        const float inv_s = __expf(-lsg);
                        const float zz    = (x[(size_t)row * MD + m] - mu) * inv_s;
                        lacc += (0.5f * zz * zz + lsg + HALF_L2PI) * mk;
                    }
                }
                if (q == 0) {
                    float past = 0.f;
                    for (int c2 = 0; c2 < S_SZ; ++c2)
                        past = fmaf(he_s[r * 129 + c2], hinf_s[c2], past);
                    const float ti = time_inf[0], bi = base_int[0];
                    const float dt = t_in[(size_t)row * 2 + 1];
                    const float term1 = past + ti * dt + bi;
                    const float tll = term1 + (__expf(past + bi) - __expf(term1)) / ti;
                    lacc += GAMMA_F * (-tll) * mk;
                }
            }
            __syncthreads();   // he_s/hsT reuse safety for next tile
        }
        // block reduce -> one atomic
        #pragma unroll
        for (int off = 32; off > 0; off >>= 1) lacc += __shfl_down(lacc, off, 64);
        if ((tid & 63) == 0) red[tid >> 6] = lacc;
        __syncthreads();
        if (tid == 0) {
            float sum = 0.f;
            #pragma unroll
            for (int w = 0; w < 6; ++w) sum += red[w];
            atomicAdd(out, sum);
        }
    }
}

extern "C" void kernel_launch(void* const* d_in, const int* in_sizes, int n_in,
                              void* d_out, int out_size, void* d_ws, size_t ws_size,
                              hipStream_t stream) {
    const float* x       = (const float*)d_in[0];
    const float* t_in    = (const float*)d_in[1];
    const float* mask    = (const float*)d_in[2];
    const float* W_embed = (const float*)d_in[3];
    const float* b_embed = (const float*)d_in[4];
    const float* W_ih    = (const float*)d_in[5];
    const float* b_ih    = (const float*)d_in[6];
    const float* W_hh    = (const float*)d_in[7];
    const float* b_hh    = (const float*)d_in[8];
    const float* W_he    = (const float*)d_in[9];
    const float* b_he    = (const float*)d_in[10];
    const float* W_mu    = (const float*)d_in[11];
    const float* b_mu    = (const float*)d_in[12];
    const float* W_lv    = (const float*)d_in[13];
    const float* b_lv    = (const float*)d_in[14];
    const float* h_inf   = (const float*)d_in[15];
    const float* tinf    = (const float*)d_in[16];
    const float* bint    = (const float*)d_in[17];
    float* out = (float*)d_out;

    // ws layout (bytes), 256-aligned:
    // phi_bf16 33.5M | hs fp32 134.2M | wpack_bf16 2.36M | hx 512K | cnt 8K
    char* ws = (char*)d_ws;
    const size_t OFF_PHI = 0;
    const size_t OFF_HS  = 33554432ull;
    const size_t OFF_WP  = 167772160ull;
    const size_t OFF_HX  = 170131456ull;
    const size_t OFF_CNT = 170655744ull;
    const size_t TOTAL   = 170663936ull;
    if (ws_size < TOTAL) return;
    unsigned short* phi   = (unsigned short*)(ws + OFF_PHI);
    float*          hsbuf = (float*)(ws + OFF_HS);
    unsigned short* wpack = (unsigned short*)(ws + OFF_WP);
    unsigned*       hx    = (unsigned*)(ws + OFF_HX);
    unsigned*       cnt   = (unsigned*)(ws + OFF_CNT);

    prep<<<dim3(1536), 256, 0, stream>>>(x, W_embed, b_embed, W_ih, W_hh,
                                         wpack, phi, hx, cnt, out);

    void* args[] = {(void*)&wpack, (void*)&phi, (void*)&hx, (void*)&hsbuf,
                    (void*)&b_ih, (void*)&b_hh, (void*)&cnt,
                    (void*)&W_he, (void*)&b_he, (void*)&W_mu, (void*)&b_mu,
                    (void*)&W_lv, (void*)&b_lv, (void*)&h_inf, (void*)&tinf,
                    (void*)&bint, (void*)&x, (void*)&t_in, (void*)&mask, (void*)&out};
    hipLaunchCooperativeKernel((void*)fused_persist, dim3(256), dim3(384), args, 0, stream);
}

// Round 12
// 1631.153 us; speedup vs baseline: 1.7052x; 1.0472x over previous
//
#include <hip/hip_runtime.h>
#include <cstddef>
#include <cstdint>

// Model dims (fixed by reference)
#define T_LEN 512
#define B_SZ  128
#define MD    31
#define E_SZ  256
#define H_SZ  512
#define S_SZ  128
#define GAMMA_F 1.0f
#define LOG001   -4.605170185988091f   // log(0.01)
#define HALF_L2PI 0.9189385332046727f  // 0.5*log(2*pi)

typedef __attribute__((ext_vector_type(8))) short bf16x8;   // 8 bf16 in 4 VGPRs
typedef __attribute__((ext_vector_type(4))) float f32x4;

#define ACT_PITCH 536   // shorts: 512 + 24 pad
#define PHI_PITCH 264   // shorts: 256 + 8 pad
#define GP        36    // gate-array col pitch (floats)
#define HS_PITCH  516   // loss hs tile pitch (floats)
#define WM_PITCH  132   // loss wmu/wlv pitch (ushorts)
#define CNT_STRIDE 16   // dwords: one 64B line per counter (de-hotspot)

// ---- shared-memory union (max of recurrence 43.3KB / loss 58.2KB) ----
#define SMEM_BYTES 58240
// recurrence offsets
#define R_ACT  0
#define R_PHI  17152
#define R_GS   34048
// loss offsets
#define L_HST  0
#define L_HES  33024
#define L_WMU  41280
#define L_WLV  49464
#define L_HINF 57648

__device__ inline unsigned short f2bf(float f) {   // fp32 -> bf16 bits, RNE
    union { float f; unsigned u; } v; v.f = f;
    unsigned r = v.u + 0x7FFFu + ((v.u >> 16) & 1u);
    return (unsigned short)(r >> 16);
}
__device__ inline float bf2f(unsigned short u) {
    union { unsigned u; float f; } v; v.u = (unsigned)u << 16; return v.f;
}
__device__ inline unsigned long long llc_load_u64(const unsigned long long* p) {
    return __hip_atomic_load(p, __ATOMIC_RELAXED, __HIP_MEMORY_SCOPE_AGENT);
}
__device__ inline unsigned llc_load_u32(const unsigned* p) {
    return __hip_atomic_load(p, __ATOMIC_RELAXED, __HIP_MEMORY_SCOPE_AGENT);
}

// ---------------- single prep kernel: pack_w + embed_phi + zero(hx buf0, cnt, out) ----------
// blocks 0..511: pack weights (first 64 also zero hx buf0; block 0 zeros cnt+out)
// blocks 512..1535: embed (identical math to the proven embed_phi)
__global__ __launch_bounds__(256) void prep(
    const float* __restrict__ x, const float* __restrict__ W_embed,
    const float* __restrict__ b_embed,
    const float* __restrict__ W_ih, const float* __restrict__ W_hh,
    unsigned short* __restrict__ wpack, unsigned short* __restrict__ phi,
    unsigned* __restrict__ hx, unsigned* __restrict__ cnt, float* __restrict__ out) {
    const int blk = blockIdx.x;
    if (blk < 512) {
        // ---- pack W -> bf16: wpack[col][768] = [W_hh[col][0:512] | W_ih[col][0:256]] ----
        const int n = 1536 * 768;
        for (int i = blk * 256 + threadIdx.x; i < n; i += 512 * 256) {
            int col = i / 768, k = i - col * 768;
            float v = (k < H_SZ) ? W_hh[col * H_SZ + k] : W_ih[col * E_SZ + (k - H_SZ)];
            wpack[i] = f2bf(v);
        }
        if (blk < 64) {            // zero hx buf0: 65536 u32 over 64 blocks
            #pragma unroll
            for (int k = 0; k < 4; ++k) hx[blk * 1024 + k * 256 + threadIdx.x] = 0u;
        }
        if (blk == 0) {            // zero cnt (128*CNT_STRIDE u32) + out
            for (int k = threadIdx.x; k < 128 * CNT_STRIDE; k += 256) cnt[k] = 0u;
            if (threadIdx.x == 0) out[0] = 0.f;
        }
    } else {
        // ---- embed: phi[row][e] = bf16(relu(b_embed[e] + x[row]·W_embed[e])) ----
        __shared__ float xs[8][32];
        const int e = threadIdx.x;
        float w[MD];
        #pragma unroll
        for (int m = 0; m < MD; ++m) w[m] = W_embed[e * MD + m];
        const float be = b_embed[e];
        const int nblocks = (T_LEN * B_SZ) / 8;
        for (int rb = blk - 512; rb < nblocks; rb += 1024) {
            const int r0 = rb * 8;
            if (threadIdx.x < 8 * MD)
                xs[threadIdx.x / MD][threadIdx.x % MD] = x[(size_t)r0 * MD + threadIdx.x];
            __syncthreads();
            #pragma unroll
            for (int i = 0; i < 8; ++i) {
                float acc = be;
                #pragma unroll
                for (int m = 0; m < MD; ++m) acc = fmaf(xs[i][m], w[m], acc);
                phi[(size_t)(r0 + i) * E_SZ + e] = f2bf(fmaxf(acc, 0.f));
            }
            __syncthreads();
        }
    }
}

// ---------------- fused persistent kernel: 128 recurrence blocks + 128 loss blocks ----------
// R11 structure (proven 1630 µs steady, VGPR 100) + ONE change: the 8 phi-part MFMAs are
// computed BEFORE the h-poll (phi_s[buf] is stable since last iteration's commit + sync B),
// taking them off the post-poll critical path. Identical arithmetic and summation order.
__global__ __launch_bounds__(384) void fused_persist(
    const unsigned short* __restrict__ wpack, const unsigned short* __restrict__ phi,
    unsigned* __restrict__ hx, float* __restrict__ hs,
    const float* __restrict__ b_ih, const float* __restrict__ b_hh,
    unsigned* __restrict__ cnt,
    const float* __restrict__ W_he, const float* __restrict__ b_he,
    const float* __restrict__ W_mu, const float* __restrict__ b_mu,
    const float* __restrict__ W_lv, const float* __restrict__ b_lv,
    const float* __restrict__ h_inf, const float* __restrict__ time_inf,
    const float* __restrict__ base_int, const float* __restrict__ x,
    const float* __restrict__ t_in, const float* __restrict__ mask,
    float* __restrict__ out) {
    __shared__ __align__(16) char smem[SMEM_BYTES];
    const int tid = threadIdx.x;

    if (blockIdx.x < 128) {
        // ================= RECURRENCE PATH =================
        short* act_s = (short*)(smem + R_ACT);
        short* phi_s0 = (short*)(smem + R_PHI);
        short* phi_s1 = (short*)(smem + R_PHI) + 16 * PHI_PITCH;
        float* g_s = (float*)(smem + R_GS);     // [4][16*GP]

        const int bt = blockIdx.x & 7, ct = blockIdx.x >> 3;
        const int b0 = bt * 16, j0 = ct * 32;
        const int wid = tid >> 6, L = tid & 63;
        const int gt = wid >> 1, ch = wid & 1;
        const int n_loc = L & 15, kb2 = L >> 4;
        const int a_row = L & 15;

        const unsigned short* __restrict__ wrow =
            wpack + (size_t)(gt * 512 + j0 + ch * 16 + n_loc) * 768;
        bf16x8 Bf[24];
        #pragma unroll
        for (int i = 0; i < 24; ++i) Bf[i] = *(const bf16x8*)(wrow + i * 32 + kb2 * 8);

        const int g_row = tid >> 5, g_col = tid & 31;
        float bias_r = 0.f, bias_z = 0.f, bias_xn = 0.f, bias_hn = 0.f;
        if (tid < 256) {
            const int j = j0 + g_col;
            bias_r  = b_ih[j] + b_hh[j];
            bias_z  = b_ih[512 + j] + b_hh[512 + j];
            bias_xn = b_ih[1024 + j];
            bias_hn = b_hh[1024 + j];
        }
        float hold1 = 0.f, hold2 = 0.f;

        // prefetch phi t=0
        #pragma unroll
        for (int it = 0; it < 3; ++it) {
            const int c = tid + it * 384;
            if (c < 1024) {
                const int m = c >> 6, q = c & 63;
                *(unsigned long long*)(phi_s0 + m * PHI_PITCH + q * 4) =
                    *(const unsigned long long*)(phi + ((size_t)(b0 + m)) * E_SZ + q * 4);
            }
        }
        __syncthreads();

        for (int t = 0; t < T_LEN - 1; ++t) {
            const int buf = t & 1;
            const short* phi_cur = buf ? phi_s1 : phi_s0;
            const unsigned tg = (unsigned)t & 0xFFFFu;

            // (A) phi-part MFMAs FIRST — off the post-poll critical path.
            // phi_s[buf] is stable: committed before last iteration's sync B.
            f32x4 accP = {0.f, 0.f, 0.f, 0.f};
            {
                const short* prow = phi_cur + a_row * PHI_PITCH;
                #pragma unroll
                for (int i = 16; i < 24; ++i) {
                    bf16x8 a = *(const bf16x8*)(prow + (i - 16) * 32 + kb2 * 8);
                    accP = __builtin_amdgcn_mfma_f32_16x16x32_bf16(a, Bf[i], accP, 0, 0, 0);
                }
            }

            // (B) staging + implicit barrier: poll tagged h words (throttled retries)
            const unsigned long long* hx64 =
                (const unsigned long long*)hx + ((size_t)(buf * 8 + bt)) * 4096;
            unsigned long long v[11];
            #pragma unroll
            for (int it = 0; it < 11; ++it) {
                const int c = tid + it * 384;
                if (c < 4096) v[it] = llc_load_u64(hx64 + c);
            }
            while (true) {
                unsigned bad = 0;
                #pragma unroll
                for (int it = 0; it < 11; ++it) {
                    const int c = tid + it * 384;
                    if (c < 4096) {
                        const unsigned t0 = (unsigned)v[it] & 0xFFFFu;
                        const unsigned t1 = (unsigned)(v[it] >> 32) & 0xFFFFu;
                        if ((t0 ^ tg) | (t1 ^ tg)) bad |= (1u << it);
                    }
                }
                if (bad == 0) break;
                __builtin_amdgcn_s_sleep(1);   // throttle spin traffic at the LLC
                #pragma unroll
                for (int it = 0; it < 11; ++it)
                    if (bad & (1u << it)) v[it] = llc_load_u64(hx64 + tid + it * 384);
            }
            #pragma unroll
            for (int it = 0; it < 11; ++it) {
                const int c = tid + it * 384;
                if (c < 4096) {
                    const int ctp = c >> 8, w = c & 255, row = w >> 4, colp = w & 15;
                    const unsigned lo = (unsigned)(v[it] >> 16) & 0xFFFFu;
                    const unsigned hi = (unsigned)(v[it] >> 48) & 0xFFFFu;
                    *(unsigned*)(act_s + row * ACT_PITCH + ctp * 32 + colp * 2) = lo | (hi << 16);
                }
            }
            __syncthreads();
            // publish: hs rows <= t are at LLC (drained by the sync above)
            if (tid == 0 && t)
                __hip_atomic_store(cnt + blockIdx.x * CNT_STRIDE, (unsigned)t,
                                   __ATOMIC_RELAXED, __HIP_MEMORY_SCOPE_AGENT);

            // next phi prefetch (held in regs)
            unsigned long long pv[3];
            const int tn = t + 1;
            if (tn < T_LEN - 1) {
                #pragma unroll
                for (int it = 0; it < 3; ++it) {
                    const int c = tid + it * 384;
                    if (c < 1024) {
                        const int m = c >> 6, q = c & 63;
                        pv[it] = *(const unsigned long long*)(
                            phi + ((size_t)tn * B_SZ + b0 + m) * E_SZ + q * 4);
                    }
                }
            }

            // (C) h-part MFMAs: split accumulate chains (even/odd k-blocks), merge accP
            {
                const short* arow = act_s + a_row * ACT_PITCH;
                f32x4 acc0 = {0.f, 0.f, 0.f, 0.f};
                f32x4 acc1 = {0.f, 0.f, 0.f, 0.f};
                #pragma unroll
                for (int i = 0; i < 16; i += 2) {
                    bf16x8 a0 = *(const bf16x8*)(arow + i * 32 + kb2 * 8);
                    bf16x8 a1 = *(const bf16x8*)(arow + (i + 1) * 32 + kb2 * 8);
                    acc0 = __builtin_amdgcn_mfma_f32_16x16x32_bf16(a0, Bf[i], acc0, 0, 0, 0);
                    acc1 = __builtin_amdgcn_mfma_f32_16x16x32_bf16(a1, Bf[i + 1], acc1, 0, 0, 0);
                }
                if (gt < 2) {
                    #pragma unroll
                    for (int i2 = 0; i2 < 4; ++i2)
                        g_s[gt * 16 * GP + ((L >> 4) * 4 + i2) * GP + ch * 16 + n_loc] =
                            acc0[i2] + acc1[i2] + accP[i2];
                } else {
                    #pragma unroll
                    for (int i2 = 0; i2 < 4; ++i2) {
                        const int idx = ((L >> 4) * 4 + i2) * GP + ch * 16 + n_loc;
                        g_s[2 * 16 * GP + idx] = acc0[i2] + acc1[i2];   // hn
                        g_s[3 * 16 * GP + idx] = accP[i2];              // xn
                    }
                }
            }

            // commit prefetched phi
            if (tn < T_LEN - 1) {
                short* pbuf = (tn & 1) ? phi_s1 : phi_s0;
                #pragma unroll
                for (int it = 0; it < 3; ++it) {
                    const int c = tid + it * 384;
                    if (c < 1024) {
                        const int m = c >> 6, q = c & 63;
                        *(unsigned long long*)(pbuf + m * PHI_PITCH + q * 4) = pv[it];
                    }
                }
            }
            __syncthreads();

            // gate math + state update + tagged store
            if (tid < 256) {
                const int nb = (t + 1) & 1;
                unsigned* hxdst = hx + ((size_t)(nb * 8 + bt) * 16 + ct) * 512;
                #pragma unroll
                for (int half = 0; half < 2; ++half) {
                    const int row = g_row + half * 8;
                    const int idx = row * GP + g_col;
                    float& hold = half ? hold2 : hold1;
                    const float pre_r = g_s[0 * 16 * GP + idx] + bias_r;
                    const float pre_z = g_s[1 * 16 * GP + idx] + bias_z;
                    const float hn    = g_s[2 * 16 * GP + idx] + bias_hn;
                    const float xn    = g_s[3 * 16 * GP + idx] + bias_xn;
                    const float r = 1.f / (1.f + __expf(-pre_r));
                    const float z = 1.f / (1.f + __expf(-pre_z));
                    const float e2 = __expf(-2.f * fmaf(r, hn, xn));
                    const float n = (1.f - e2) / (1.f + e2);          // tanh
                    const float hnew = fmaf(z, hold - n, n);          // (1-z)*n + z*h
                    hold = hnew;
                    __hip_atomic_store(
                        hs + (size_t)(t + 1) * B_SZ * H_SZ + (size_t)(b0 + row) * H_SZ + j0 + g_col,
                        hnew, __ATOMIC_RELAXED, __HIP_MEMORY_SCOPE_AGENT);
                    if (t < T_LEN - 2)
                        __hip_atomic_store(hxdst + row * 32 + g_col,
                                           ((unsigned)f2bf(hnew) << 16) | ((unsigned)(t + 1) & 0xFFFFu),
                                           __ATOMIC_RELAXED, __HIP_MEMORY_SCOPE_AGENT);
                }
            }
        }
        __syncthreads();   // drain final hs stores
        if (tid == 0)
            __hip_atomic_store(cnt + blockIdx.x * CNT_STRIDE, (unsigned)(T_LEN - 1),
                               __ATOMIC_RELAXED, __HIP_MEMORY_SCOPE_AGENT);
    } else {
        // ================= LOSS PATH =================
        float* hsT  = (float*)(smem + L_HST);            // [16][HS_PITCH]
        float* he_s = (float*)(smem + L_HES);            // [16][129]
        unsigned short* wmu_s = (unsigned short*)(smem + L_WMU);  // [31][WM_PITCH] bf16
        unsigned short* wlv_s = (unsigned short*)(smem + L_WLV);
        float* hinf_s = (float*)(smem + L_HINF);         // [128]
        float* red    = (float*)(smem + L_HINF) + 128;   // [6]

        const int i = blockIdx.x - 128;
        const int lb = i & 7, ls = i >> 3;
        const int b0 = lb * 16;

        for (int k = tid; k < MD * S_SZ; k += 384) {
            wmu_s[(k >> 7) * WM_PITCH + (k & 127)] = f2bf(W_mu[k]);
            wlv_s[(k >> 7) * WM_PITCH + (k & 127)] = f2bf(W_lv[k]);
        }
        if (tid < S_SZ) hinf_s[tid] = h_inf[tid];
        __syncthreads();

        float lacc = 0.f;
        for (int s = 0; s < 32; ++s) {
            const int t = 1 + ls + 16 * s;
            if (t > T_LEN - 1) break;
            // wait for all 16 ct producer blocks of group lb to pass step t
            if (tid < 64) {
                while (true) {
                    unsigned cv = 0xFFFFFFFFu;
                    if (tid < 16) cv = llc_load_u32(cnt + (lb + 8 * tid) * CNT_STRIDE);
                    if (__ballot(cv >= (unsigned)t) == ~0ull) break;
                    __builtin_amdgcn_s_sleep(64);
                }
            }
            __syncthreads();
            // stage hs tile (16 rows x 512 fp32) via LLC-coherent u64 loads
            const unsigned long long* hs64 =
                (const unsigned long long*)(hs + ((size_t)t * B_SZ + b0) * H_SZ);
            #pragma unroll
            for (int it = 0; it < 11; ++it) {
                const int c = tid + it * 384;
                if (c < 4096) {
                    const int m = c >> 8, q = c & 255;   // row, u64-in-row
                    unsigned long long v = llc_load_u64(hs64 + (size_t)m * 256 + q);
                    *(unsigned long long*)(hsT + m * HS_PITCH + q * 2) = v;
                }
            }
            __syncthreads();
            // phase 1: he = relu(W_he . h + b_he)
            if (tid < 256) {
                const int c = tid & 127, rg = tid >> 7;
                const float* __restrict__ wr = W_he + (size_t)c * H_SZ;
                float acc[8];
                #pragma unroll
                for (int ii = 0; ii < 8; ++ii) acc[ii] = b_he[c];
                for (int k = 0; k < H_SZ; k += 4) {
                    const float4 w4 = *(const float4*)(wr + k);
                    #pragma unroll
                    for (int ii = 0; ii < 8; ++ii) {
                        const float4 h4 = *(const float4*)(hsT + (rg * 8 + ii) * HS_PITCH + k);
                        acc[ii] = fmaf(w4.x, h4.x, acc[ii]);
                        acc[ii] = fmaf(w4.y, h4.y, acc[ii]);
                        acc[ii] = fmaf(w4.z, h4.z, acc[ii]);
                        acc[ii] = fmaf(w4.w, h4.w, acc[ii]);
                    }
                }
                #pragma unroll
                for (int ii = 0; ii < 8; ++ii)
                    he_s[(rg * 8 + ii) * 129 + c] = fmaxf(acc[ii], 0.f);
            }
            __syncthreads();
            // phase 2: markers + time LL
            if (tid < 256) {
                const int r = tid >> 4, q = tid & 15;
                const int row = t * B_SZ + b0 + r;
                const float mk = mask[row];
                #pragma unroll
                for (int pass = 0; pass < 2; ++pass) {
                    const int m = q + pass * 16;
                    if (m < MD) {
                        float mu = b_mu[m], lv = b_lv[m];
                        for (int c2 = 0; c2 < S_SZ; ++c2) {
                            const float h = he_s[r * 129 + c2];
                            mu = fmaf(h, bf2f(wmu_s[m * WM_PITCH + c2]), mu);
                            lv = fmaf(h, bf2f(wlv_s[m * WM_PITCH + c2]), lv);
                        }
                        const float lsg   = fmaxf(0.5f * lv, LOG001);
                        const float inv_s = __expf(-lsg);
                        const float zz    = (x[(size_t)row * MD + m] - mu) * inv_s;
                        lacc += (0.5f * zz * zz + lsg + HALF_L2PI) * mk;
                    }
                }
                if (q == 0) {
                    float past = 0.f;
                    for (int c2 = 0; c2 < S_SZ; ++c2)
                        past = fmaf(he_s[r * 129 + c2], hinf_s[c2], past);
                    const float ti = time_inf[0], bi = base_int[0];
                    const float dt = t_in[(size_t)row * 2 + 1];
                    const float term1 = past + ti * dt + bi;
                    const float tll = term1 + (__expf(past + bi) - __expf(term1)) / ti;
                    lacc += GAMMA_F * (-tll) * mk;
                }
            }
            __syncthreads();   // he_s/hsT reuse safety for next tile
        }
        // block reduce -> one atomic
        #pragma unroll
        for (int off = 32; off > 0; off >>= 1) lacc += __shfl_down(lacc, off, 64);
        if ((tid & 63) == 0) red[tid >> 6] = lacc;
        __syncthreads();
        if (tid == 0) {
            float sum = 0.f;
            #pragma unroll
            for (int w = 0; w < 6; ++w) sum += red[w];
            atomicAdd(out, sum);
        }
    }
}

extern "C" void kernel_launch(void* const* d_in, const int* in_sizes, int n_in,
                              void* d_out, int out_size, void* d_ws, size_t ws_size,
                              hipStream_t stream) {
    const float* x       = (const float*)d_in[0];
    const float* t_in    = (const float*)d_in[1];
    const float* mask    = (const float*)d_in[2];
    const float* W_embed = (const float*)d_in[3];
    const float* b_embed = (const float*)d_in[4];
    const float* W_ih    = (const float*)d_in[5];
    const float* b_ih    = (const float*)d_in[6];
    const float* W_hh    = (const float*)d_in[7];
    const float* b_hh    = (const float*)d_in[8];
    const float* W_he    = (const float*)d_in[9];
    const float* b_he    = (const float*)d_in[10];
    const float* W_mu    = (const float*)d_in[11];
    const float* b_mu    = (const float*)d_in[12];
    const float* W_lv    = (const float*)d_in[13];
    const float* b_lv    = (const float*)d_in[14];
    const float* h_inf   = (const float*)d_in[15];
    const float* tinf    = (const float*)d_in[16];
    const float* bint    = (const float*)d_in[17];
    float* out = (float*)d_out;

    // ws layout (bytes), 256-aligned:
    // phi_bf16 33.5M | hs fp32 134.2M | wpack_bf16 2.36M | hx 512K | cnt 8K
    char* ws = (char*)d_ws;
    const size_t OFF_PHI = 0;
    const size_t OFF_HS  = 33554432ull;
    const size_t OFF_WP  = 167772160ull;
    const size_t OFF_HX  = 170131456ull;
    const size_t OFF_CNT = 170655744ull;
    const size_t TOTAL   = 170663936ull;
    if (ws_size < TOTAL) return;
    unsigned short* phi   = (unsigned short*)(ws + OFF_PHI);
    float*          hsbuf = (float*)(ws + OFF_HS);
    unsigned short* wpack = (unsigned short*)(ws + OFF_WP);
    unsigned*       hx    = (unsigned*)(ws + OFF_HX);
    unsigned*       cnt   = (unsigned*)(ws + OFF_CNT);

    prep<<<dim3(1536), 256, 0, stream>>>(x, W_embed, b_embed, W_ih, W_hh,
                                         wpack, phi, hx, cnt, out);

    void* args[] = {(void*)&wpack, (void*)&phi, (void*)&hx, (void*)&hsbuf,
                    (void*)&b_ih, (void*)&b_hh, (void*)&cnt,
                    (void*)&W_he, (void*)&b_he, (void*)&W_mu, (void*)&b_mu,
                    (void*)&W_lv, (void*)&b_lv, (void*)&h_inf, (void*)&tinf,
                    (void*)&bint, (void*)&x, (void*)&t_in, (void*)&mask, (void*)&out};
    hipLaunchCooperativeKernel((void*)fused_persist, dim3(256), dim3(384), args, 0, stream);
}